// Round 6
// baseline (99.257 us; speedup 1.0000x reference)
//
#include <hip/hip_runtime.h>

// DepthToSpace 3D, block=2, channels_last.
// in:  (4, 32, 64, 64, 128) fp32   out: (4, 64, 128, 128, 16) fp32
// out[n, 2z+dz, 2y+dy, 2x+dx, c] = in[n, z, y, x, (dz*4+dy*2+dx)*16 + c]
//
// R1 structure (direct permuted copy, 1 f4 per load/store, writes fully
// coalesced, reads 128B chunks) + BLOCK-LOCAL coarsening x4:
//   idx = blockIdx*1024 + j*256 + t
// Per instruction: same contiguous-1KB-per-wave pattern as R1. Per thread:
// 4 independent load/store pairs within a 16KB window -> 4x VMEM in flight,
// no far-apart power-of-2 fronts (R4's mistake: stride N4/4 = 64MB aliasing).

typedef float f32x4 __attribute__((ext_vector_type(4)));

__global__ __launch_bounds__(256) void d2s_kernel(const f32x4* __restrict__ in4,
                                                  f32x4* __restrict__ out4) {
    unsigned int base = blockIdx.x * 1024u + threadIdx.x;

#pragma unroll
    for (int j = 0; j < 4; ++j) {
        unsigned int idx = base + (unsigned int)j * 256u;

        // Output float4 index decomposition.
        // out float layout: (n, Z(64), Y(128), X(128), c(16)) -> float4: c4 in [0,4)
        unsigned int c4 = idx & 3u;
        unsigned int t  = idx >> 2;
        unsigned int X  = t & 127u;  t >>= 7;
        unsigned int Y  = t & 127u;  t >>= 7;
        unsigned int Z  = t & 63u;
        unsigned int n  = t >> 6;

        unsigned int x = X >> 1, dx = X & 1u;
        unsigned int y = Y >> 1, dy = Y & 1u;
        unsigned int z = Z >> 1, dz = Z & 1u;
        unsigned int i = dz * 4u + dy * 2u + dx;

        // input float4 index: (((n*32+z)*64+y)*64+x)*32 + i*4 + c4
        unsigned int in_idx = ((((n * 32u + z) * 64u + y) * 64u + x) << 5) + (i << 2) + c4;

        out4[idx] = in4[in_idx];
    }
}

extern "C" void kernel_launch(void* const* d_in, const int* in_sizes, int n_in,
                              void* d_out, int out_size, void* d_ws, size_t ws_size,
                              hipStream_t stream) {
    const f32x4* in4 = (const f32x4*)d_in[0];
    f32x4* out4 = (f32x4*)d_out;
    // 16,777,216 float4 / (256 threads * 4 per thread) = 16384 blocks
    int block = 256;
    int grid = 16384;
    d2s_kernel<<<grid, block, 0, stream>>>(in4, out4);
}

// Round 7
// 96.005 us; speedup vs baseline: 1.0339x; 1.0339x over previous
//
#include <hip/hip_runtime.h>

// DepthToSpace 3D, block=2, channels_last.
// in:  (4, 32, 64, 64, 128) fp32   out: (4, 64, 128, 128, 16) fp32
// out[n, 2z+dz, 2y+dy, 2x+dx, c] = in[n, z, y, x, (dz*4+dy*2+dx)*16 + c]
//
// R1 structure — empirical optimum over 6-round search:
//   R1 direct 1-f4/thread:            95.4 us  <-- this kernel
//   R3 +nt +coarsen(stride 64MB):    106.5 us
//   R4 coarsen(stride 64MB), no nt:  118.0 us
//   R5 LDS-staged, seq both sides:    99.0 us
//   R6 coarsen block-local 16KB:      99.3 us
// Writes perfectly coalesced/contiguous; reads 8x128B chunks per wave
// (full cache lines, zero over-fetch). 5.63 TB/s ~= 95% of the
// pattern-independent mixed-stream ceiling established by R5.

typedef float f32x4 __attribute__((ext_vector_type(4)));

__global__ __launch_bounds__(256) void d2s_kernel(const f32x4* __restrict__ in4,
                                                  f32x4* __restrict__ out4) {
    unsigned int idx = blockIdx.x * 256u + threadIdx.x;

    // Output float4 index decomposition.
    // out float layout: (n, Z(64), Y(128), X(128), c(16)) -> float4: c4 in [0,4)
    unsigned int c4 = idx & 3u;
    unsigned int t  = idx >> 2;
    unsigned int X  = t & 127u;  t >>= 7;
    unsigned int Y  = t & 127u;  t >>= 7;
    unsigned int Z  = t & 63u;
    unsigned int n  = t >> 6;

    unsigned int x = X >> 1, dx = X & 1u;
    unsigned int y = Y >> 1, dy = Y & 1u;
    unsigned int z = Z >> 1, dz = Z & 1u;
    unsigned int i = dz * 4u + dy * 2u + dx;

    // input float4 index: (((n*32+z)*64+y)*64+x)*32 + i*4 + c4
    unsigned int in_idx = ((((n * 32u + z) * 64u + y) * 64u + x) << 5) + (i << 2) + c4;

    out4[idx] = in4[in_idx];
}

extern "C" void kernel_launch(void* const* d_in, const int* in_sizes, int n_in,
                              void* d_out, int out_size, void* d_ws, size_t ws_size,
                              hipStream_t stream) {
    const f32x4* in4 = (const f32x4*)d_in[0];
    f32x4* out4 = (f32x4*)d_out;
    int n4 = out_size / 4;              // 16,777,216
    int block = 256;
    int grid = n4 / block;              // 65536, exact
    d2s_kernel<<<grid, block, 0, stream>>>(in4, out4);
}